// Round 1
// baseline (605.308 us; speedup 1.0000x reference)
//
#include <hip/hip_runtime.h>

// Problem constants (match reference)
constexpr int Bx = 64;
constexpr int Lx = 1024;
constexpr int Dx = 1024;
constexpr int Sx = 32;

constexpr int DC   = 256;          // D-columns per block
constexpr int NSUB = 4;            // l-phases (separate LDS accumulator copies)
constexpr int ROWS = Sx + 1;       // row 0 absorbs label 0 (ignored)
constexpr int NBLK = Bx * (Dx / DC);  // 256 blocks

// ---------------------------------------------------------------------------
// Kernel 1: per (batch, D-chunk) block.
//  Phase A: segmented sum of text_feats into LDS acc[NSUB][ROWS][DC].
//    sub = wave-uniform l-phase; thread owns exactly one (sub, col) lane so
//    no two threads ever hit the same LDS address. ds_add_f32 (no return)
//    keeps the LDS pipe free of RAW dependency chains.
//  Phase B: per-label partial dot(V, seg), ||seg||^2, ||V||^2 over this
//    256-col chunk (additive across D-chunks), wave-reduced, stored to ws.
// ---------------------------------------------------------------------------
__global__ __launch_bounds__(1024, 1) void seg_dot_kernel(
    const int*   __restrict__ attrs,   // [B][L]
    const float* __restrict__ text,    // [B][L][D]
    const float* __restrict__ vgs,     // [B][S][D]
    float* __restrict__ pnum,          // [NBLK][S]
    float* __restrict__ pns2,          // [NBLK][S]
    float* __restrict__ pnv2,          // [NBLK][S]
    int*   __restrict__ wcnt)          // [B][S]
{
    __shared__ float acc[NSUB * ROWS * DC];   // 132 KB
    __shared__ int   hist[ROWS];

    const int tid    = threadIdx.x;
    const int bid    = blockIdx.x;
    const int b      = bid >> 2;
    const int dchunk = bid & 3;
    const int d0     = dchunk * DC;

    // zero LDS accumulators
    #pragma unroll
    for (int i = tid; i < NSUB * ROWS * DC; i += 1024) acc[i] = 0.0f;
    if (tid < ROWS) hist[tid] = 0;
    __syncthreads();

    // wave-uniform l-phase (tid>>8 is constant within a 64-lane wave since
    // 256-thread groups align with wave boundaries)
    const int sub = __builtin_amdgcn_readfirstlane(tid >> 8);
    const int col = tid & (DC - 1);

    const int*   __restrict__ arow = attrs + b * Lx;
    const float* __restrict__ tcol = text + (size_t)b * Lx * Dx + d0 + col;
    float* __restrict__ asub = acc + sub * (ROWS * DC) + col;

    #pragma unroll 8
    for (int l = sub; l < Lx; l += NSUB) {
        const int   a = arow[l];               // wave-uniform -> s_load (scalar cache)
        const float v = tcol[(size_t)l * Dx];  // coalesced 256B/wave
        atomicAdd(&asub[a * DC], v);           // ds_add_f32, collision-free
    }

    // per-batch label histogram (only D-chunk 0 blocks; L == blockDim)
    if (dchunk == 0) {
        atomicAdd(&hist[arow[tid]], 1);
    }
    __syncthreads();
    if (dchunk == 0 && tid >= 1 && tid <= Sx) {
        wcnt[b * Sx + (tid - 1)] = hist[tid];
    }

    // Phase B: partial reductions per label for this d-chunk
    const int w    = tid >> 6;   // wave id 0..15
    const int lane = tid & 63;
    const int c    = lane * 4;   // 64 lanes x float4 = 256 cols

    #pragma unroll
    for (int si = 0; si < 2; ++si) {
        const int s = w + si * 16;            // label 0..31
        const float4 vv =
            *(const float4*)(vgs + (size_t)(b * Sx + s) * Dx + d0 + c);
        float m0 = 0.f, m1 = 0.f, m2 = 0.f, m3 = 0.f;
        #pragma unroll
        for (int sb = 0; sb < NSUB; ++sb) {
            const float* ap = acc + sb * (ROWS * DC) + (s + 1) * DC + c;
            m0 += ap[0]; m1 += ap[1]; m2 += ap[2]; m3 += ap[3];
        }
        float num = m0 * vv.x + m1 * vv.y + m2 * vv.z + m3 * vv.w;
        float ns2 = m0 * m0 + m1 * m1 + m2 * m2 + m3 * m3;
        float nv2 = vv.x * vv.x + vv.y * vv.y + vv.z * vv.z + vv.w * vv.w;
        #pragma unroll
        for (int off = 32; off > 0; off >>= 1) {
            num += __shfl_xor(num, off, 64);
            ns2 += __shfl_xor(ns2, off, 64);
            nv2 += __shfl_xor(nv2, off, 64);
        }
        if (lane == 0) {
            const int idx = bid * Sx + s;
            pnum[idx] = num;
            pns2[idx] = ns2;
            pnv2[idx] = nv2;
        }
    }
}

// ---------------------------------------------------------------------------
// Kernel 2: fold the 4 D-chunk partials per (b,s), apply torch cosine eps
// semantics, reduce to the scalar loss.
//   cos = (num/cnt) / max(||V|| * ||seg||/cnt, eps)
//       =  num       / max(||V|| * ||seg||, eps*cnt)
// ---------------------------------------------------------------------------
__global__ __launch_bounds__(256) void finalize_kernel(
    const float* __restrict__ pnum, const float* __restrict__ pns2,
    const float* __restrict__ pnv2, const int* __restrict__ wcnt,
    float* __restrict__ out)
{
    const int tid = threadIdx.x;
    float lsum = 0.0f;
    #pragma unroll
    for (int k = 0; k < (Bx * Sx) / 256; ++k) {   // 8 pairs/thread
        const int p = k * 256 + tid;              // (b,s) flat index
        const int b = p >> 5;
        const int s = p & 31;
        float num = 0.f, ns2 = 0.f, nv2 = 0.f;
        #pragma unroll
        for (int dc = 0; dc < 4; ++dc) {
            const int idx = (b * 4 + dc) * Sx + s;
            num += pnum[idx];
            ns2 += pns2[idx];
            nv2 += pnv2[idx];
        }
        const float cnt   = (float)wcnt[p];
        const float denom = fmaxf(sqrtf(nv2) * sqrtf(ns2), 1e-8f * cnt);
        lsum += num / denom;
    }
    #pragma unroll
    for (int off = 32; off > 0; off >>= 1) lsum += __shfl_xor(lsum, off, 64);

    __shared__ float red[4];
    if ((tid & 63) == 0) red[tid >> 6] = lsum;
    __syncthreads();
    if (tid == 0) {
        const float total = red[0] + red[1] + red[2] + red[3];
        out[0] = 1.0f - total * (1.0f / (float)(Bx * Sx));
    }
}

// ---------------------------------------------------------------------------
extern "C" void kernel_launch(void* const* d_in, const int* in_sizes, int n_in,
                              void* d_out, int out_size, void* d_ws, size_t ws_size,
                              hipStream_t stream) {
    const int*   attrs = (const int*)d_in[0];
    const float* text  = (const float*)d_in[1];
    const float* vgs   = (const float*)d_in[2];
    float* out = (float*)d_out;

    float* pnum = (float*)d_ws;                 // 256*32 f32 = 32 KB
    float* pns2 = pnum + NBLK * Sx;             // 32 KB
    float* pnv2 = pns2 + NBLK * Sx;             // 32 KB
    int*   wcnt = (int*)(pnv2 + NBLK * Sx);     // 8 KB

    seg_dot_kernel<<<NBLK, 1024, 0, stream>>>(attrs, text, vgs,
                                              pnum, pns2, pnv2, wcnt);
    finalize_kernel<<<1, 256, 0, stream>>>(pnum, pns2, pnv2, wcnt, out);
}

// Round 2
// 371.125 us; speedup vs baseline: 1.6310x; 1.6310x over previous
//
#include <hip/hip_runtime.h>

// Problem constants (match reference)
constexpr int Bx = 64;
constexpr int Lx = 1024;
constexpr int Dx = 1024;
constexpr int Sx = 32;

constexpr int DC   = 256;             // D-columns per block
constexpr int ROWS = Sx + 1;          // row 0 absorbs label 0 (ignored)
constexpr int NBLK = Bx * (Dx / DC);  // 256 blocks = 1/CU
constexpr int PREF = 8;               // loads in flight per wave

// ---------------------------------------------------------------------------
// Kernel 1: per (batch, D-chunk) block, 1024 threads = 16 waves.
//  Prologue: counting-sort token indices by label (hist -> wave scan ->
//    scatter). spack[pos] = (label<<16)|l, labels ascending (label 0 first).
//  Phase A: wave w owns sorted slice [w*64, w*64+64). Equal labels are
//    adjacent, so accumulate text rows in a VGPR float4 and flush to LDS
//    acc[label][col] only at label boundaries (~3 flushes/wave, vs one LDS
//    atomic per element in round 1 -- that was the 342us bottleneck).
//    Labels via readfirstlane -> scalar branches + SGPR load addresses.
//    8-deep prefetch: 8 outstanding dwordx4/wave x 16 waves saturates HBM.
//  Phase B: per-label partial dot(V,seg), ||seg||^2, ||V||^2 over this
//    256-col chunk (additive across D-chunks), wave-reduced, stored to ws.
// ---------------------------------------------------------------------------
__global__ __launch_bounds__(1024, 1) void seg_dot_kernel(
    const int*   __restrict__ attrs,   // [B][L]
    const float* __restrict__ text,    // [B][L][D]
    const float* __restrict__ vgs,     // [B][S][D]
    float* __restrict__ pnum,          // [NBLK][S]
    float* __restrict__ pns2,          // [NBLK][S]
    float* __restrict__ pnv2,          // [NBLK][S]
    int*   __restrict__ wcnt)          // [B][S]
{
    __shared__ float acc[ROWS * DC];   // 33 KB
    __shared__ int   spack[Lx];        // 4 KB: (label<<16)|l, sorted by label
    __shared__ int   hist[ROWS];
    __shared__ int   cursor[ROWS];

    const int tid    = threadIdx.x;
    const int bid    = blockIdx.x;
    const int b      = bid >> 2;
    const int dchunk = bid & 3;
    const int d0     = dchunk * DC;

    for (int i = tid; i < ROWS * DC; i += 1024) acc[i] = 0.0f;
    if (tid < ROWS) hist[tid] = 0;
    __syncthreads();

    // histogram (tid == token index since L == blockDim)
    const int my_a = attrs[b * Lx + tid];
    atomicAdd(&hist[my_a], 1);
    __syncthreads();

    // exclusive prefix over 33 bins, one wave, shfl scan
    if (tid < 64) {
        const int h = (tid < ROWS) ? hist[tid] : 0;
        int v = h;
        #pragma unroll
        for (int off = 1; off < 64; off <<= 1) {
            const int u = __shfl_up(v, off, 64);
            if (tid >= off) v += u;
        }
        if (tid < ROWS) cursor[tid] = v - h;   // exclusive prefix
    }
    __syncthreads();

    // scatter into sorted order
    const int pos = atomicAdd(&cursor[my_a], 1);
    spack[pos] = (my_a << 16) | tid;
    if (dchunk == 0 && tid >= 1 && tid <= Sx) {
        wcnt[b * Sx + (tid - 1)] = hist[tid];
    }
    __syncthreads();

    // Phase A
    const int w    = tid >> 6;
    const int lane = tid & 63;
    const float* __restrict__ tbase =
        text + (size_t)b * Lx * Dx + d0 + lane * 4;

    float4 a4  = make_float4(0.f, 0.f, 0.f, 0.f);
    int    cur = 0;

    for (int k0 = 0; k0 < 64; k0 += PREF) {
        int    pk[PREF];
        float4 v[PREF];
        #pragma unroll
        for (int j = 0; j < PREF; ++j)
            pk[j] = __builtin_amdgcn_readfirstlane(spack[w * 64 + k0 + j]);
        #pragma unroll
        for (int j = 0; j < PREF; ++j) {
            const int l = pk[j] & 0xffff;
            v[j] = *(const float4*)(tbase + (size_t)l * Dx);
        }
        #pragma unroll
        for (int j = 0; j < PREF; ++j) {
            const int s = pk[j] >> 16;
            if (s != cur) {                    // scalar branch (s,cur in SGPRs)
                atomicAdd(&acc[cur * DC + lane * 4 + 0], a4.x);
                atomicAdd(&acc[cur * DC + lane * 4 + 1], a4.y);
                atomicAdd(&acc[cur * DC + lane * 4 + 2], a4.z);
                atomicAdd(&acc[cur * DC + lane * 4 + 3], a4.w);
                a4  = make_float4(0.f, 0.f, 0.f, 0.f);
                cur = s;
            }
            if (s != 0) {                      // label 0 rows ignored
                a4.x += v[j].x; a4.y += v[j].y;
                a4.z += v[j].z; a4.w += v[j].w;
            }
        }
    }
    atomicAdd(&acc[cur * DC + lane * 4 + 0], a4.x);
    atomicAdd(&acc[cur * DC + lane * 4 + 1], a4.y);
    atomicAdd(&acc[cur * DC + lane * 4 + 2], a4.z);
    atomicAdd(&acc[cur * DC + lane * 4 + 3], a4.w);
    __syncthreads();

    // Phase B: partial reductions per label for this d-chunk
    #pragma unroll
    for (int si = 0; si < 2; ++si) {
        const int s = w + si * 16;             // label 0..31
        const float4 vv =
            *(const float4*)(vgs + (size_t)(b * Sx + s) * Dx + d0 + lane * 4);
        const float4 m = *(const float4*)(&acc[(s + 1) * DC + lane * 4]);
        float num = m.x * vv.x + m.y * vv.y + m.z * vv.z + m.w * vv.w;
        float ns2 = m.x * m.x + m.y * m.y + m.z * m.z + m.w * m.w;
        float nv2 = vv.x * vv.x + vv.y * vv.y + vv.z * vv.z + vv.w * vv.w;
        #pragma unroll
        for (int off = 32; off > 0; off >>= 1) {
            num += __shfl_xor(num, off, 64);
            ns2 += __shfl_xor(ns2, off, 64);
            nv2 += __shfl_xor(nv2, off, 64);
        }
        if (lane == 0) {
            const int idx = bid * Sx + s;
            pnum[idx] = num;
            pns2[idx] = ns2;
            pnv2[idx] = nv2;
        }
    }
}

// ---------------------------------------------------------------------------
// Kernel 2: fold the 4 D-chunk partials per (b,s), apply torch cosine eps
// semantics, reduce to the scalar loss.
//   cos = (num/cnt) / max(||V|| * ||seg||/cnt, eps)
//       =  num       / max(||V|| * ||seg||, eps*cnt)
// ---------------------------------------------------------------------------
__global__ __launch_bounds__(256) void finalize_kernel(
    const float* __restrict__ pnum, const float* __restrict__ pns2,
    const float* __restrict__ pnv2, const int* __restrict__ wcnt,
    float* __restrict__ out)
{
    const int tid = threadIdx.x;
    float lsum = 0.0f;
    #pragma unroll
    for (int k = 0; k < (Bx * Sx) / 256; ++k) {   // 8 pairs/thread
        const int p = k * 256 + tid;              // (b,s) flat index
        const int b = p >> 5;
        const int s = p & 31;
        float num = 0.f, ns2 = 0.f, nv2 = 0.f;
        #pragma unroll
        for (int dc = 0; dc < 4; ++dc) {
            const int idx = (b * 4 + dc) * Sx + s;
            num += pnum[idx];
            ns2 += pns2[idx];
            nv2 += pnv2[idx];
        }
        const float cnt   = (float)wcnt[p];
        const float denom = fmaxf(sqrtf(nv2) * sqrtf(ns2), 1e-8f * cnt);
        lsum += num / denom;
    }
    #pragma unroll
    for (int off = 32; off > 0; off >>= 1) lsum += __shfl_xor(lsum, off, 64);

    __shared__ float red[4];
    if ((tid & 63) == 0) red[tid >> 6] = lsum;
    __syncthreads();
    if (tid == 0) {
        const float total = red[0] + red[1] + red[2] + red[3];
        out[0] = 1.0f - total * (1.0f / (float)(Bx * Sx));
    }
}

// ---------------------------------------------------------------------------
extern "C" void kernel_launch(void* const* d_in, const int* in_sizes, int n_in,
                              void* d_out, int out_size, void* d_ws, size_t ws_size,
                              hipStream_t stream) {
    const int*   attrs = (const int*)d_in[0];
    const float* text  = (const float*)d_in[1];
    const float* vgs   = (const float*)d_in[2];
    float* out = (float*)d_out;

    float* pnum = (float*)d_ws;                 // 256*32 f32 = 32 KB
    float* pns2 = pnum + NBLK * Sx;             // 32 KB
    float* pnv2 = pns2 + NBLK * Sx;             // 32 KB
    int*   wcnt = (int*)(pnv2 + NBLK * Sx);     // 8 KB

    seg_dot_kernel<<<NBLK, 1024, 0, stream>>>(attrs, text, vgs,
                                              pnum, pns2, pnv2, wcnt);
    finalize_kernel<<<1, 256, 0, stream>>>(pnum, pns2, pnv2, wcnt, out);
}

// Round 3
// 370.580 us; speedup vs baseline: 1.6334x; 1.0015x over previous
//
#include <hip/hip_runtime.h>

// Problem constants (match reference)
constexpr int Bx = 64;
constexpr int Lx = 1024;
constexpr int Dx = 1024;
constexpr int Sx = 32;

constexpr int DC   = 128;             // D-columns per block (8 chunks)
constexpr int NCH  = Dx / DC;         // 8
constexpr int ROWS = Sx + 1;          // row 0 absorbs label 0 (ignored)
constexpr int NBLK = Bx * NCH;        // 512 blocks = 2/CU
constexpr int PREF = 8;               // rolling loads in flight per wave

// ---------------------------------------------------------------------------
// Kernel 0: counting-sort token indices by label, once per batch.
//  spack_g[b][pos] = (label<<16)|l, labels ascending. Also writes wcnt.
// ---------------------------------------------------------------------------
__global__ __launch_bounds__(1024) void sort_kernel(
    const int* __restrict__ attrs,   // [B][L]
    int* __restrict__ spack_g,       // [B][L]
    int* __restrict__ wcnt)          // [B][S]
{
    __shared__ int hist[ROWS];
    __shared__ int cursor[ROWS];
    const int b   = blockIdx.x;
    const int tid = threadIdx.x;

    if (tid < ROWS) hist[tid] = 0;
    __syncthreads();
    const int a = attrs[b * Lx + tid];     // tid == token index (L == blockDim)
    atomicAdd(&hist[a], 1);
    __syncthreads();
    if (tid < 64) {                        // exclusive scan over 33 bins
        const int h = (tid < ROWS) ? hist[tid] : 0;
        int v = h;
        #pragma unroll
        for (int off = 1; off < 64; off <<= 1) {
            const int u = __shfl_up(v, off, 64);
            if (tid >= off) v += u;
        }
        if (tid < ROWS) cursor[tid] = v - h;
    }
    __syncthreads();
    const int pos = atomicAdd(&cursor[a], 1);
    spack_g[b * Lx + pos] = (a << 16) | tid;
    if (tid >= 1 && tid <= Sx) wcnt[b * Sx + (tid - 1)] = hist[tid];
}

// ---------------------------------------------------------------------------
// Kernel 1: per (batch, D-chunk) block, 1024 threads = 16 waves, 2 blocks/CU.
//  Each wave owns 64 sorted tokens. Packs preloaded into one VGPR (pv);
//  readlane(pv, j) extracts them as SGPRs -- no LDS in the hot loop.
//  Rolling 8-deep prefetch: consume buf[j&7], immediately reissue j+8.
//  Equal labels adjacent -> accumulate in a float2 VGPR, flush to LDS
//  acc[label][col] only at label boundaries (scalar branch).
// ---------------------------------------------------------------------------
__global__ __launch_bounds__(1024, 8) void seg_dot_kernel(
    const float* __restrict__ text,    // [B][L][D]
    const float* __restrict__ vgs,     // [B][S][D]
    const int*   __restrict__ spack_g, // [B][L]
    float* __restrict__ pnum,          // [NBLK][S]
    float* __restrict__ pns2,          // [NBLK][S]
    float* __restrict__ pnv2)          // [NBLK][S]
{
    __shared__ float acc[ROWS * DC];   // ~16.9 KB

    const int tid    = threadIdx.x;
    const int bid    = blockIdx.x;
    const int b      = bid >> 3;
    const int dchunk = bid & 7;
    const int d0     = dchunk * DC;
    const int w      = tid >> 6;
    const int lane   = tid & 63;

    for (int i = tid; i < ROWS * DC; i += 1024) acc[i] = 0.0f;

    // all 64 packs for this wave, one coalesced load, kept in a VGPR
    const int pv = spack_g[b * Lx + w * 64 + lane];

    const float* __restrict__ tbase =
        text + (size_t)b * Lx * Dx + d0 + lane * 2;

    __syncthreads();   // acc zeroed

    float2 buf[PREF];
    int    pk[PREF];

    #pragma unroll
    for (int j = 0; j < PREF; ++j) {           // prologue: fill the pipe
        const int p = __builtin_amdgcn_readlane(pv, j);
        pk[j] = p;
        if (p >> 16) buf[j] = *(const float2*)(tbase + (size_t)(p & 0xffff) * Dx);
    }

    float2 a2  = make_float2(0.f, 0.f);
    int    cur = 0;

    #pragma unroll
    for (int j = 0; j < 64; ++j) {
        const int    slot = j & (PREF - 1);
        const int    p    = pk[slot];
        const int    s    = p >> 16;
        const float2 vv   = buf[slot];         // waits on this slot's load only
        if (j + PREF < 64) {                   // reissue into freed slot
            const int pn = __builtin_amdgcn_readlane(pv, j + PREF);
            pk[slot] = pn;
            if (pn >> 16)
                buf[slot] = *(const float2*)(tbase + (size_t)(pn & 0xffff) * Dx);
        }
        if (s != cur) {                        // scalar branch: flush boundary
            atomicAdd(&acc[cur * DC + lane * 2 + 0], a2.x);
            atomicAdd(&acc[cur * DC + lane * 2 + 1], a2.y);
            a2  = make_float2(0.f, 0.f);
            cur = s;
        }
        if (s != 0) { a2.x += vv.x; a2.y += vv.y; }
    }
    atomicAdd(&acc[cur * DC + lane * 2 + 0], a2.x);
    atomicAdd(&acc[cur * DC + lane * 2 + 1], a2.y);
    __syncthreads();

    // Phase B: per-label partials for this d-chunk (additive across chunks)
    #pragma unroll
    for (int si = 0; si < 2; ++si) {
        const int s = w + si * 16;             // label 0..31
        const float2 vv =
            *(const float2*)(vgs + (size_t)(b * Sx + s) * Dx + d0 + lane * 2);
        const float2 m = *(const float2*)(&acc[(s + 1) * DC + lane * 2]);
        float num = m.x * vv.x + m.y * vv.y;
        float ns2 = m.x * m.x + m.y * m.y;
        float nv2 = vv.x * vv.x + vv.y * vv.y;
        #pragma unroll
        for (int off = 32; off > 0; off >>= 1) {
            num += __shfl_xor(num, off, 64);
            ns2 += __shfl_xor(ns2, off, 64);
            nv2 += __shfl_xor(nv2, off, 64);
        }
        if (lane == 0) {
            const int idx = bid * Sx + s;
            pnum[idx] = num;
            pns2[idx] = ns2;
            pnv2[idx] = nv2;
        }
    }
}

// ---------------------------------------------------------------------------
// Kernel 2: fold the 8 D-chunk partials per (b,s), torch cosine eps
// semantics, reduce to the scalar loss.
//   cos = num / max(||V|| * ||seg_sum||, eps*cnt)
// ---------------------------------------------------------------------------
__global__ __launch_bounds__(256) void finalize_kernel(
    const float* __restrict__ pnum, const float* __restrict__ pns2,
    const float* __restrict__ pnv2, const int* __restrict__ wcnt,
    float* __restrict__ out)
{
    const int tid = threadIdx.x;
    float lsum = 0.0f;
    #pragma unroll
    for (int k = 0; k < (Bx * Sx) / 256; ++k) {   // 8 pairs/thread
        const int p = k * 256 + tid;              // (b,s) flat index
        const int b = p >> 5;
        const int s = p & 31;
        float num = 0.f, ns2 = 0.f, nv2 = 0.f;
        #pragma unroll
        for (int dc = 0; dc < NCH; ++dc) {
            const int idx = (b * NCH + dc) * Sx + s;
            num += pnum[idx];
            ns2 += pns2[idx];
            nv2 += pnv2[idx];
        }
        const float cnt   = (float)wcnt[p];
        const float denom = fmaxf(sqrtf(nv2) * sqrtf(ns2), 1e-8f * cnt);
        lsum += num / denom;
    }
    #pragma unroll
    for (int off = 32; off > 0; off >>= 1) lsum += __shfl_xor(lsum, off, 64);

    __shared__ float red[4];
    if ((tid & 63) == 0) red[tid >> 6] = lsum;
    __syncthreads();
    if (tid == 0) {
        const float total = red[0] + red[1] + red[2] + red[3];
        out[0] = 1.0f - total * (1.0f / (float)(Bx * Sx));
    }
}

// ---------------------------------------------------------------------------
extern "C" void kernel_launch(void* const* d_in, const int* in_sizes, int n_in,
                              void* d_out, int out_size, void* d_ws, size_t ws_size,
                              hipStream_t stream) {
    const int*   attrs = (const int*)d_in[0];
    const float* text  = (const float*)d_in[1];
    const float* vgs   = (const float*)d_in[2];
    float* out = (float*)d_out;

    int*   spack = (int*)d_ws;                   // 64*1024 i32 = 256 KB
    float* pnum  = (float*)(spack + Bx * Lx);    // 512*32 f32 = 64 KB
    float* pns2  = pnum + NBLK * Sx;             // 64 KB
    float* pnv2  = pns2 + NBLK * Sx;             // 64 KB
    int*   wcnt  = (int*)(pnv2 + NBLK * Sx);     // 8 KB

    sort_kernel<<<Bx, 1024, 0, stream>>>(attrs, spack, wcnt);
    seg_dot_kernel<<<NBLK, 1024, 0, stream>>>(text, vgs, spack,
                                              pnum, pns2, pnv2);
    finalize_kernel<<<1, 256, 0, stream>>>(pnum, pns2, pnv2, wcnt, out);
}